// Round 9
// baseline (291.962 us; speedup 1.0000x reference)
//
#include <hip/hip_runtime.h>
#include <math.h>

#define D 256
#define NROW 16384
#define KCODE 8192
#define MARGIN 4.05e-3f   // one-sided bf16 split: u=2^-8=3.906e-3 + residual/accum slack

typedef __attribute__((ext_vector_type(8))) short short8;
typedef __attribute__((ext_vector_type(4))) float f32x4;

__device__ __forceinline__ float dot4(float4 a, float4 b) {
  return a.x * b.x + a.y * b.y + a.z * b.z + a.w * b.w;
}
__device__ __forceinline__ float wave_sum(float s) {
#pragma unroll
  for (int off = 32; off; off >>= 1) s += __shfl_xor(s, off, 64);
  return s;
}
__device__ __forceinline__ float wave_min_f(float v) {
#pragma unroll
  for (int off = 32; off; off >>= 1) v = fminf(v, __shfl_xor(v, off, 64));
  return v;
}
__device__ __forceinline__ unsigned short f2bf(float x) {
  unsigned int u = __float_as_uint(x);
  return (unsigned short)((u + 0x7fffu + ((u >> 16) & 1u)) >> 16);
}
__device__ __forceinline__ float bf2f(unsigned short h) {
  return __uint_as_float(((unsigned int)h) << 16);
}
__device__ __forceinline__ void async16(const void* g, void* l) {
  __builtin_amdgcn_global_load_lds(
      (const __attribute__((address_space(1))) unsigned int*)g,
      (__attribute__((address_space(3))) unsigned int*)l, 16, 0, 0);
}

// ---------- combined prep: blocks [0,2048) emb -> [hi] (256 sh); [2048,6144) z -> [hi|lo] (512 sh) ----------
__global__ __launch_bounds__(256) void k_prep(const float* __restrict__ emb,
                                              const float* __restrict__ z,
                                              float* __restrict__ emb_n,
                                              float* __restrict__ e2,
                                              unsigned short* __restrict__ Bb,
                                              unsigned short* __restrict__ Ab) {
  const int b = blockIdx.x;
  const int w = threadIdx.x >> 6, l = threadIdx.x & 63;
  if (b < 2048) {
    int row = b * 4 + w;
    float4 v = ((const float4*)(emb + (size_t)row * D))[l];
    float s = wave_sum(dot4(v, v));
    float inv = 1.0f / sqrtf(s + 1e-12f);
    v.x *= inv; v.y *= inv; v.z *= inv; v.w *= inv;
    ((float4*)(emb_n + (size_t)row * D))[l] = v;
    float s2 = wave_sum(dot4(v, v));
    if (l == 0) e2[row] = s2;
    ushort4 hi = {f2bf(v.x), f2bf(v.y), f2bf(v.z), f2bf(v.w)};
    *(ushort4*)(Bb + (size_t)row * 256 + 4 * l) = hi;   // codes: [hi] only
  } else {
    int row = (b - 2048) * 4 + w;
    float4 v = ((const float4*)(z + (size_t)row * D))[l];
    float s = wave_sum(dot4(v, v));
    float inv = 1.0f / sqrtf(s + 1e-12f);
    v.x *= inv; v.y *= inv; v.z *= inv; v.w *= inv;
    ushort4 hi = {f2bf(v.x), f2bf(v.y), f2bf(v.z), f2bf(v.w)};
    float4 rh = {bf2f(hi.x), bf2f(hi.y), bf2f(hi.z), bf2f(hi.w)};
    ushort4 lo = {f2bf(v.x - rh.x), f2bf(v.y - rh.y), f2bf(v.z - rh.z), f2bf(v.w - rh.w)};
    unsigned short* p = Ab + (size_t)row * 512 + 4 * l;
    *(ushort4*)(p) = hi;          // z: [hi | lo]
    *(ushort4*)(p + 256) = lo;
  }
}

__device__ __forceinline__ void merge2(float& d1, int& k1, float& d2, int& k2,
                                       float od1, int ok1, float od2, int ok2) {
  bool w1 = (od1 < d1) || (od1 == d1 && ok1 < k1);
  float n1 = w1 ? od1 : d1; int nk1 = w1 ? ok1 : k1;
  float c  = w1 ? d1 : od1; int ck  = w1 ? k1 : ok1;
  float c2 = w1 ? od2 : d2; int ck2 = w1 ? ok2 : k2;
  bool w2 = (c2 < c) || (c2 == c && ck2 < ck);
  d1 = n1; k1 = nk1;
  d2 = w2 ? c2 : c; k2 = w2 ? ck2 : ck;
}

// ---------- 256x128 tile GEMM (codes x z), K'=512 one-sided split ----------
// 512 thr = 8 waves (4 code-quadrants x 2 z-halves), wave tile 64x64 (same
// register footprint as R8 -> still 16 waves/CU, register-pinned), but
// MFMA-per-barrier doubles (256) and staging drops to 192 B/MFMA (was 512).
// LDS 48 KB -> 2 blocks/CU. XCD owns 4 code-tiles (512 KB slab, L2-resident).
__global__ __launch_bounds__(512, 4) void k_gemm_argmin5(
    const unsigned short* __restrict__ Cb,   // codes [hi], 256 sh/row
    const unsigned short* __restrict__ Zb,   // z [hi|lo], 512 sh/row
    const float* __restrict__ e2, float4* __restrict__ top2) {
  __shared__ unsigned short As[256 * 64];    // code tile, 32 KB
  __shared__ unsigned short Bs[128 * 64];    // z tile, 16 KB
  const int tid = threadIdx.x, w = tid >> 6, l = tid & 63;
  const int wm = w >> 1, wn = w & 1;         // wm: code quadrant 0..3, wn: z half
  const int quad = l >> 4, col = l & 15;
  const int xcd = blockIdx.x & 7;
  const int j = blockIdx.x >> 3;
  const int ct = xcd * 4 + (j & 3);          // code tile 0..31 (256 codes each)
  const int zt = j >> 2;                     // z tile 0..127
  const int c0 = ct * 256;
  const size_t z0 = (size_t)zt * 128;

  const int srow = tid >> 3, su = tid & 7;   // srow 0..63
  const int g = su ^ (srow & 7);
  const unsigned short* gA = Cb + ((size_t)c0 + srow) * 256 + g * 8;
  const unsigned short* gB = Zb + (z0 + srow) * 512 + g * 8;
  char* dA = (char*)As + srow * 128 + su * 16;
  char* dB = (char*)Bs + srow * 128 + su * 16;

  f32x4 acc[4][4] = {};
  const int ub = col & 7;

  for (int s = 0; s < 8; ++s) {
    const int kA = (s & 3) * 64;   // codes re-read hi for both K-halves
    const int kB = s * 64;
#pragma unroll
    for (int p = 0; p < 4; ++p)
      async16(gA + (size_t)p * 64 * 256 + kA, dA + p * 8192);
#pragma unroll
    for (int p = 0; p < 2; ++p)
      async16(gB + (size_t)p * 64 * 512 + kB, dB + p * 8192);
    __syncthreads();
#pragma unroll
    for (int par = 0; par < 2; ++par) {
      const int uoff = (((par * 4 + quad) ^ ub) << 4);
      short8 af[4], bf[4];
#pragma unroll
      for (int mf = 0; mf < 4; ++mf)
        af[mf] = *(const short8*)((const char*)As + (wm * 64 + mf * 16 + col) * 128 + uoff);
#pragma unroll
      for (int nf = 0; nf < 4; ++nf)
        bf[nf] = *(const short8*)((const char*)Bs + (wn * 64 + nf * 16 + col) * 128 + uoff);
#pragma unroll
      for (int mf = 0; mf < 4; ++mf)
#pragma unroll
        for (int nf = 0; nf < 4; ++nf)
          acc[mf][nf] = __builtin_amdgcn_mfma_f32_16x16x32_bf16(af[mf], bf[nf], acc[mf][nf], 0, 0, 0);
    }
    __syncthreads();
  }

  float e2r[16];
#pragma unroll
  for (int mf = 0; mf < 4; ++mf)
#pragma unroll
    for (int v = 0; v < 4; ++v)
      e2r[mf * 4 + v] = e2[c0 + wm * 64 + mf * 16 + quad * 4 + v];

  float4* mbuf = (float4*)As;  // 4 wm x 128 z = 8 KB reuse (post-barrier)
#pragma unroll
  for (int nf = 0; nf < 4; ++nf) {
    float d1 = 1e30f, d2 = 1e30f; int k1 = 0, k2 = 0;
#pragma unroll
    for (int mf = 0; mf < 4; ++mf)
#pragma unroll
      for (int v = 0; v < 4; ++v) {
        float d = fmaf(-2.0f, acc[mf][nf][v], e2r[mf * 4 + v]);
        int kc = c0 + wm * 64 + mf * 16 + quad * 4 + v;
        bool lt1 = d < d1, lt2 = d < d2;
        d2 = lt1 ? d1 : (lt2 ? d : d2);
        k2 = lt1 ? k1 : (lt2 ? kc : k2);
        d1 = lt1 ? d : d1;
        k1 = lt1 ? kc : k1;
      }
#pragma unroll
    for (int m = 16; m < 64; m <<= 1) {
      float od1 = __shfl_xor(d1, m, 64); int ok1 = __shfl_xor(k1, m, 64);
      float od2 = __shfl_xor(d2, m, 64); int ok2 = __shfl_xor(k2, m, 64);
      merge2(d1, k1, d2, k2, od1, ok1, od2, ok2);
    }
    if (quad == 0)
      mbuf[wm * 128 + wn * 64 + nf * 16 + col] =
          make_float4(d1, d2, __int_as_float(k1), __int_as_float(k2));
  }
  __syncthreads();
  if (tid < 128) {
    const int zz = tid;
    float4 a = mbuf[zz];
    float d1 = a.x, d2 = a.y; int k1 = __float_as_int(a.z), k2 = __float_as_int(a.w);
#pragma unroll
    for (int q = 1; q < 4; ++q) {
      float4 b = mbuf[q * 128 + zz];
      merge2(d1, k1, d2, k2, b.x, __float_as_int(b.z), b.y, __float_as_int(b.w));
    }
    // row-stride stays 64 entries (only first 32 used) so refine's lane-exact
    // read-before-write aliasing with out0 remains byte-identical.
    top2[(z0 + zz) * 64 + ct] =
        make_float4(d1, d2, __int_as_float(k1), __int_as_float(k2));
  }
}

// ---------- fused refine + gather + STE + per-row loss; 32 sublists/row ----------
__global__ __launch_bounds__(256) void k_refine_gather(
    const float* __restrict__ z, const float* __restrict__ emb_n,
    const float* __restrict__ e2, const float4* __restrict__ top2,
    float* __restrict__ out0, float* __restrict__ idx_out,
    float* __restrict__ lsum, int* __restrict__ wl_row,
    unsigned long long* __restrict__ wl_mask, double* __restrict__ wl_best,
    int* __restrict__ wl_bk, int* __restrict__ n_flag) {
  __shared__ float zr[4][D];
  const int w = threadIdx.x >> 6, l = threadIdx.x & 63;
  const int row = blockIdx.x * 4 + w;
  float4 zv = ((const float4*)(z + (size_t)row * D))[l];
  float s = wave_sum(dot4(zv, zv));
  float inv = 1.0f / sqrtf(s + 1e-12f);
  float4 zn = make_float4(zv.x * inv, zv.y * inv, zv.z * inv, zv.w * inv);
  ((float4*)zr[w])[l] = zn;
  __syncthreads();

  float ad1 = 1e30f, ad2 = 1e30f;
  int ck1 = 0, ck2 = 0;
  if (l < 32) {  // lane l reads the exact 16 bytes it will later overwrite
    float4 e = top2[(size_t)row * 64 + l];
    ad1 = e.x; ad2 = e.y;
    ck1 = __float_as_int(e.z); ck2 = __float_as_int(e.w);
  }
  const float d1g = wave_min_f(ad1);
  const float win = d1g + 2.0f * MARGIN;

  double best = 1e300; int bk = 0x7fffffff;
  unsigned long long m1 = __ballot(ad1 <= win);
  unsigned long long m2 = __ballot(ad2 <= win);  // == sublist rescan mask (bits<32)
#pragma unroll 1
  for (int slot = 0; slot < 2; ++slot) {
    unsigned long long mm = slot ? m2 : m1;
    while (mm) {
      int ln = __builtin_ctzll(mm); mm &= mm - 1;
      int k = __shfl(slot ? ck2 : ck1, ln, 64);
      float4 e4 = ((const float4*)(emb_n + (size_t)k * D))[l];
      float4 z4 = ((const float4*)zr[w])[l];
      double p = (double)e4.x * (double)z4.x + (double)e4.y * (double)z4.y +
                 (double)e4.z * (double)z4.z + (double)e4.w * (double)z4.w;
#pragma unroll
      for (int off = 32; off; off >>= 1) p += __shfl_xor(p, off, 64);
      double dd = (double)e2[k] - 2.0 * p;
      if (dd < best || (dd == best && k < bk)) { best = dd; bk = k; }
    }
  }
  float4 q = ((const float4*)(emb_n + (size_t)bk * D))[l];
  float4 o;
  o.x = zv.x + (q.x - zv.x); o.y = zv.y + (q.y - zv.y);
  o.z = zv.z + (q.z - zv.z); o.w = zv.w + (q.w - zv.w);
  ((float4*)(out0 + (size_t)row * D))[l] = o;
  float dx = q.x - zn.x, dy = q.y - zn.y, dz = q.z - zn.z, dw = q.w - zn.w;
  float lp = wave_sum(dx * dx + dy * dy + dz * dz + dw * dw);
  if (l == 0) {
    lsum[row] = lp;
    idx_out[row] = (float)bk;
    if (m2) {  // some sublist's 3rd+ code could still be in the window
      int p = atomicAdd(n_flag, 1);
      wl_row[p] = row; wl_mask[p] = m2; wl_best[p] = best; wl_bk[p] = bk;
    }
  }
}

// ---------- exact fp64 rescan of flagged sublists (256 codes each, 1 thr/code) ----------
__global__ __launch_bounds__(256) void k_rescan(
    const float* __restrict__ z, const float* __restrict__ emb_n,
    const float* __restrict__ e2, const int* __restrict__ wl_row,
    const unsigned long long* __restrict__ wl_mask,
    const double* __restrict__ wl_best, const int* __restrict__ wl_bk,
    const int* __restrict__ n_flag, float* __restrict__ idx_out,
    float* __restrict__ out0, float* __restrict__ lsum) {
  __shared__ float zr[D];
  __shared__ double sd[4];
  __shared__ int si[4];
  __shared__ int s_bk;
  const int tid = threadIdx.x;
  const int nf = *n_flag;
  for (int wi = blockIdx.x; wi < nf; wi += gridDim.x) {
    const int row = wl_row[wi];
    unsigned long long mask = wl_mask[wi];   // block-uniform
    __syncthreads();  // protect zr across iterations
    if (tid < 64) {
      float4 zv = ((const float4*)(z + (size_t)row * D))[tid];
      float s = wave_sum(dot4(zv, zv));
      float inv = 1.0f / sqrtf(s + 1e-12f);
      ((float4*)zr)[tid] = make_float4(zv.x * inv, zv.y * inv, zv.z * inv, zv.w * inv);
    }
    __syncthreads();
    double best = wl_best[wi]; int bk = wl_bk[wi];
    const float4* zf = (const float4*)zr;
    while (mask) {
      const int sl = __builtin_ctzll(mask); mask &= mask - 1;
      const int code = (sl << 8) + tid;    // 256 codes, one per thread
      const float4* ev = (const float4*)(emb_n + (size_t)code * D);
      double a0 = 0.0, a1 = 0.0, a2 = 0.0, a3 = 0.0;
#pragma unroll 4
      for (int i = 0; i < 64; i += 4) {
        float4 e0 = ev[i], e1 = ev[i + 1], ex = ev[i + 2], e3 = ev[i + 3];
        float4 z0 = zf[i], z1 = zf[i + 1], zx = zf[i + 2], z3 = zf[i + 3];
        a0 += (double)e0.x * (double)z0.x + (double)e0.y * (double)z0.y +
              (double)e0.z * (double)z0.z + (double)e0.w * (double)z0.w;
        a1 += (double)e1.x * (double)z1.x + (double)e1.y * (double)z1.y +
              (double)e1.z * (double)z1.z + (double)e1.w * (double)z1.w;
        a2 += (double)ex.x * (double)zx.x + (double)ex.y * (double)zx.y +
              (double)ex.z * (double)zx.z + (double)ex.w * (double)zx.w;
        a3 += (double)e3.x * (double)z3.x + (double)e3.y * (double)z3.y +
              (double)e3.z * (double)z3.z + (double)e3.w * (double)z3.w;
      }
      double dd = (double)e2[code] - 2.0 * ((a0 + a1) + (a2 + a3));
      if (dd < best || (dd == best && code < bk)) { best = dd; bk = code; }
    }
#pragma unroll
    for (int off = 32; off; off >>= 1) {
      double od = __shfl_xor(best, off, 64); int ok = __shfl_xor(bk, off, 64);
      if (od < best || (od == best && ok < bk)) { best = od; bk = ok; }
    }
    if ((tid & 63) == 0) { sd[tid >> 6] = best; si[tid >> 6] = bk; }
    __syncthreads();
    if (tid == 0) {
#pragma unroll
      for (int q = 1; q < 4; ++q)
        if (sd[q] < best || (sd[q] == best && si[q] < bk)) { best = sd[q]; bk = si[q]; }
      s_bk = bk;
      idx_out[row] = (float)bk;
    }
    __syncthreads();
    const int fk = s_bk;
    if (tid < 64) {
      float4 zv = ((const float4*)(z + (size_t)row * D))[tid];
      float4 zn = ((const float4*)zr)[tid];
      float4 q = ((const float4*)(emb_n + (size_t)fk * D))[tid];
      float4 o;
      o.x = zv.x + (q.x - zv.x); o.y = zv.y + (q.y - zv.y);
      o.z = zv.z + (q.z - zv.z); o.w = zv.w + (q.w - zv.w);
      ((float4*)(out0 + (size_t)row * D))[tid] = o;
      float dx = q.x - zn.x, dy = q.y - zn.y, dz = q.z - zn.z, dw = q.w - zn.w;
      float lp = wave_sum(dx * dx + dy * dy + dz * dz + dw * dw);
      if (tid == 0) lsum[row] = lp;
    }
  }
}

// ---------- final reduce: loss = 1.25 * sum(lsum) / (N*D) ----------
__global__ __launch_bounds__(256) void k_reduce(const float* __restrict__ lsum,
                                                float* __restrict__ loss_out,
                                                float inv_cnt) {
  __shared__ float ws4[4];
  float s = 0.0f;
  const float4* p = (const float4*)lsum;
  for (int i = threadIdx.x; i < NROW / 4; i += 256) {
    float4 v = p[i];
    s += (v.x + v.y) + (v.z + v.w);
  }
  s = wave_sum(s);
  if ((threadIdx.x & 63) == 0) ws4[threadIdx.x >> 6] = s;
  __syncthreads();
  if (threadIdx.x == 0) {
    float m = ((ws4[0] + ws4[1]) + (ws4[2] + ws4[3])) * inv_cnt;
    *loss_out = 0.25f * m + m;
  }
}

// ---------- fallback fp32 path (round-1, proven) ----------
__device__ __forceinline__ int sw_f(int row, int d4) { return row * D + 4 * (d4 ^ (row & 7)); }
__global__ __launch_bounds__(256, 1) void k_argmin_f32(const float* __restrict__ z,
                                                       const float* __restrict__ emb_n,
                                                       const float* __restrict__ e2,
                                                       float* __restrict__ idx_out, int K) {
  extern __shared__ float smem[];
  float* zs = smem; float* es = smem + 64 * D;
  int tid = threadIdx.x; int w = tid >> 6, l = tid & 63;
  size_t r0 = (size_t)blockIdx.x * 64;
#pragma unroll
  for (int i = 0; i < 16; ++i) {
    int row = 4 * i + w;
    float4 v = ((const float4*)(z + (r0 + row) * D))[l];
    float s = wave_sum(dot4(v, v));
    float inv = 1.0f / sqrtf(s + 1e-12f);
    v.x *= inv; v.y *= inv; v.z *= inv; v.w *= inv;
    *(float4*)(&zs[sw_f(row, l)]) = v;
  }
  __syncthreads();
  int tc = tid & 15, tr = tid >> 4;
  float bestd[4] = {1e30f, 1e30f, 1e30f, 1e30f};
  int bestk[4] = {0, 0, 0, 0};
  for (int k0 = 0; k0 < K; k0 += 64) {
#pragma unroll
    for (int i = 0; i < 16; ++i) {
      int row = 4 * i + w;
      float4 v = ((const float4*)(emb_n + (size_t)(k0 + row) * D))[l];
      *(float4*)(&es[sw_f(row, l)]) = v;
    }
    __syncthreads();
    float acc[4][4] = {};
#pragma unroll 4
    for (int d4 = 0; d4 < 64; ++d4) {
      float4 zv[4], ev[4];
#pragma unroll
      for (int i = 0; i < 4; ++i) zv[i] = *(const float4*)(&zs[sw_f(tr + 16 * i, d4)]);
#pragma unroll
      for (int jx = 0; jx < 4; ++jx) ev[jx] = *(const float4*)(&es[sw_f(tc + 16 * jx, d4)]);
#pragma unroll
      for (int i = 0; i < 4; ++i)
#pragma unroll
        for (int jx = 0; jx < 4; ++jx)
          acc[i][jx] = fmaf(zv[i].x, ev[jx].x, fmaf(zv[i].y, ev[jx].y,
                       fmaf(zv[i].z, ev[jx].z, fmaf(zv[i].w, ev[jx].w, acc[i][jx]))));
    }
#pragma unroll
    for (int jx = 0; jx < 4; ++jx) {
      int k = k0 + tc + 16 * jx;
      float ek = e2[k];
#pragma unroll
      for (int i = 0; i < 4; ++i) {
        float dd = fmaf(-2.0f, acc[i][jx], ek);
        if (dd < bestd[i]) { bestd[i] = dd; bestk[i] = k; }
      }
    }
    __syncthreads();
  }
#pragma unroll
  for (int i = 0; i < 4; ++i) {
    float dd = bestd[i]; int kkk = bestk[i];
#pragma unroll
    for (int off = 1; off < 16; off <<= 1) {
      float od = __shfl_xor(dd, off, 64); int ok = __shfl_xor(kkk, off, 64);
      if (od < dd || (od == dd && ok < kkk)) { dd = od; kkk = ok; }
    }
    if (tc == 0) idx_out[r0 + tr + 16 * i] = (float)kkk;
  }
}

__global__ __launch_bounds__(256) void k_gather(const float* __restrict__ z,
                                                const float* __restrict__ emb_n,
                                                const float* __restrict__ idx_f,
                                                float* __restrict__ out0,
                                                float* __restrict__ loss_acc) {
  __shared__ float wsum[4];
  int w = threadIdx.x >> 6, l = threadIdx.x & 63;
  int row = blockIdx.x * 4 + w;
  float4 zv = ((const float4*)(z + (size_t)row * D))[l];
  float s = wave_sum(dot4(zv, zv));
  float inv = 1.0f / sqrtf(s + 1e-12f);
  int k = (int)idx_f[row];
  float4 q = ((const float4*)(emb_n + (size_t)k * D))[l];
  float4 o;
  o.x = zv.x + (q.x - zv.x); o.y = zv.y + (q.y - zv.y);
  o.z = zv.z + (q.z - zv.z); o.w = zv.w + (q.w - zv.w);
  ((float4*)(out0 + (size_t)row * D))[l] = o;
  float dx = q.x - zv.x * inv, dy = q.y - zv.y * inv;
  float dz = q.z - zv.z * inv, dw = q.w - zv.w * inv;
  float lp = wave_sum(dx * dx + dy * dy + dz * dz + dw * dw);
  if (l == 0) wsum[w] = lp;
  __syncthreads();
  if (threadIdx.x == 0) atomicAdd(loss_acc, wsum[0] + wsum[1] + wsum[2] + wsum[3]);
}

__global__ void k_final(const float* __restrict__ loss_acc,
                        float* __restrict__ loss_out, float inv_cnt) {
  float m = *loss_acc * inv_cnt;
  *loss_out = 0.25f * m + m;
}

extern "C" void kernel_launch(void* const* d_in, const int* in_sizes, int n_in,
                              void* d_out, int out_size, void* d_ws, size_t ws_size,
                              hipStream_t stream) {
  const float* z = (const float*)d_in[0];
  const float* emb = (const float*)d_in[1];
  int N = in_sizes[0] / D;  // 16384
  int K = in_sizes[1] / D;  // 8192

  float* out0 = (float*)d_out;
  float* loss_out = out0 + (size_t)N * D;
  float* idx_out = loss_out + 1;

  char* ws = (char*)d_ws;
  float* emb_n = (float*)ws;                              // 8 MB
  float* e2 = (float*)(ws + 8388608);                     // 32 KB
  float* loss_acc = (float*)(ws + 8421376);               // 4 B (fallback)
  int* n_flag = (int*)(ws + 8421380);                     // 4 B
  float* lsum = (float*)(ws + 8421392);                   // 64 KB
  unsigned short* Bb = (unsigned short*)(ws + 8486928);   // codes [hi], 4 MB
  unsigned short* Ab = (unsigned short*)(ws + 12681232);  // z [hi|lo], 16 MB
  const size_t NEED = 29458448;
  // Ab dead after gemm -> worklist arrays (row/mask/best/bk), 384 KB total
  int* wl_row = (int*)Ab;
  unsigned long long* wl_mask = (unsigned long long*)((char*)Ab + 65536);
  double* wl_best = (double*)((char*)Ab + 196608);
  int* wl_bk = (int*)((char*)Ab + 327680);
  float4* top2 = (float4*)out0;  // 16 MB scratch in d_out; refine overwrites

  const float inv_cnt = 1.0f / (float)((size_t)N * D);
  hipMemsetAsync(loss_acc, 0, 8, stream);  // zero loss_acc + n_flag
  if (ws_size >= NEED) {
    k_prep<<<K / 4 + N / 4, 256, 0, stream>>>(emb, z, emb_n, e2, Bb, Ab);
    k_gemm_argmin5<<<(K / 256) * (N / 128), 512, 0, stream>>>(Bb, Ab, e2, top2);
    k_refine_gather<<<N / 4, 256, 0, stream>>>(z, emb_n, e2, top2, out0, idx_out,
                                               lsum, wl_row, wl_mask, wl_best,
                                               wl_bk, n_flag);
    k_rescan<<<1024, 256, 0, stream>>>(z, emb_n, e2, wl_row, wl_mask, wl_best,
                                       wl_bk, n_flag, idx_out, out0, lsum);
    k_reduce<<<1, 256, 0, stream>>>(lsum, loss_out, inv_cnt);
  } else {
    k_prep<<<K / 4 + N / 4, 256, 0, stream>>>(emb, z, emb_n, e2, Bb, Ab);
    k_argmin_f32<<<N / 64, 256, 131072, stream>>>(z, emb_n, e2, idx_out, K);
    k_gather<<<N / 4, 256, 0, stream>>>(z, emb_n, idx_out, out0, loss_acc);
    k_final<<<1, 1, 0, stream>>>(loss_acc, loss_out, inv_cnt);
  }
}

// Round 10
// 214.648 us; speedup vs baseline: 1.3602x; 1.3602x over previous
//
#include <hip/hip_runtime.h>
#include <math.h>

#define D 256
#define NROW 16384
#define KCODE 8192
#define MARGIN 1.2e-3f   // pure-fp16 product: 2*2^-11 = 9.77e-4 worst + accum slack

typedef _Float16 half8 __attribute__((ext_vector_type(8)));
typedef _Float16 half4f __attribute__((ext_vector_type(4)));
typedef __attribute__((ext_vector_type(4))) float f32x4;

__device__ __forceinline__ float dot4(float4 a, float4 b) {
  return a.x * b.x + a.y * b.y + a.z * b.z + a.w * b.w;
}
__device__ __forceinline__ float wave_sum(float s) {
#pragma unroll
  for (int off = 32; off; off >>= 1) s += __shfl_xor(s, off, 64);
  return s;
}
__device__ __forceinline__ float wave_min_f(float v) {
#pragma unroll
  for (int off = 32; off; off >>= 1) v = fminf(v, __shfl_xor(v, off, 64));
  return v;
}
__device__ __forceinline__ void async16(const void* g, void* l) {
  __builtin_amdgcn_global_load_lds(
      (const __attribute__((address_space(1))) unsigned int*)g,
      (__attribute__((address_space(3))) unsigned int*)l, 16, 0, 0);
}

// ---------- combined prep: blocks [0,2048) emb -> fp16 [hi]; [2048,6144) z -> fp16 [hi] ----------
__global__ __launch_bounds__(256) void k_prep(const float* __restrict__ emb,
                                              const float* __restrict__ z,
                                              float* __restrict__ emb_n,
                                              float* __restrict__ e2,
                                              _Float16* __restrict__ Bb,
                                              _Float16* __restrict__ Ab) {
  const int b = blockIdx.x;
  const int w = threadIdx.x >> 6, l = threadIdx.x & 63;
  if (b < 2048) {
    int row = b * 4 + w;
    float4 v = ((const float4*)(emb + (size_t)row * D))[l];
    float s = wave_sum(dot4(v, v));
    float inv = 1.0f / sqrtf(s + 1e-12f);
    v.x *= inv; v.y *= inv; v.z *= inv; v.w *= inv;
    ((float4*)(emb_n + (size_t)row * D))[l] = v;
    float s2 = wave_sum(dot4(v, v));
    if (l == 0) e2[row] = s2;
    half4f h;
    h[0] = (_Float16)v.x; h[1] = (_Float16)v.y;
    h[2] = (_Float16)v.z; h[3] = (_Float16)v.w;
    *(half4f*)(Bb + (size_t)row * 256 + 4 * l) = h;
  } else {
    int row = (b - 2048) * 4 + w;
    float4 v = ((const float4*)(z + (size_t)row * D))[l];
    float s = wave_sum(dot4(v, v));
    float inv = 1.0f / sqrtf(s + 1e-12f);
    v.x *= inv; v.y *= inv; v.z *= inv; v.w *= inv;
    half4f h;
    h[0] = (_Float16)v.x; h[1] = (_Float16)v.y;
    h[2] = (_Float16)v.z; h[3] = (_Float16)v.w;
    *(half4f*)(Ab + (size_t)row * 256 + 4 * l) = h;
  }
}

__device__ __forceinline__ void merge2(float& d1, int& k1, float& d2, int& k2,
                                       float od1, int ok1, float od2, int ok2) {
  bool w1 = (od1 < d1) || (od1 == d1 && ok1 < k1);
  float n1 = w1 ? od1 : d1; int nk1 = w1 ? ok1 : k1;
  float c  = w1 ? d1 : od1; int ck  = w1 ? k1 : ok1;
  float c2 = w1 ? od2 : d2; int ck2 = w1 ? ok2 : k2;
  bool w2 = (c2 < c) || (c2 == c && ck2 < ck);
  d1 = n1; k1 = nk1;
  d2 = w2 ? c2 : c; k2 = w2 ? ck2 : ck;
}

// ---------- 128x128 fp16 GEMM (codes x z), K'=256, fused per-(row,sublist) top-2 ----------
// R8's proven structure; 4 K-steps of BK=64. top2 layout [zt][ct][128 rows]:
// each block writes ONE contiguous 2 KB run (no 16B-scatter write amplification).
__global__ __launch_bounds__(256, 4) void k_gemm_argmin6(
    const _Float16* __restrict__ Cb,   // codes fp16, 256/row
    const _Float16* __restrict__ Zb,   // z fp16, 256/row
    const float* __restrict__ e2, float4* __restrict__ top2) {
  __shared__ _Float16 As[128 * 64];    // code tile, 16 KB
  __shared__ _Float16 Bs[128 * 64];    // z tile, 16 KB
  const int tid = threadIdx.x, w = tid >> 6, l = tid & 63;
  const int wm = w >> 1, wn = w & 1;
  const int quad = l >> 4, col = l & 15;
  const int xcd = blockIdx.x & 7;
  const int j = blockIdx.x >> 3;
  const int ct = xcd * 8 + (j & 7);          // code tile 0..63
  const int zt = j >> 3;                     // z tile 0..127
  const int c0 = ct * 128;
  const size_t z0 = (size_t)zt * 128;

  const int srow = tid >> 3, su = tid & 7;
  const int g = su ^ (srow & 7);
  const _Float16* gA = Cb + ((size_t)c0 + srow) * 256 + g * 8;
  const _Float16* gB = Zb + (z0 + srow) * 256 + g * 8;
  char* dA = (char*)As + srow * 128 + su * 16;
  char* dB = (char*)Bs + srow * 128 + su * 16;

  f32x4 acc[4][4] = {};
  const int ub = col & 7;

  for (int s = 0; s < 4; ++s) {
    const int k0 = s * 64;
#pragma unroll
    for (int p = 0; p < 4; ++p) {
      async16(gA + (size_t)p * 32 * 256 + k0, dA + p * 4096);
      async16(gB + (size_t)p * 32 * 256 + k0, dB + p * 4096);
    }
    __syncthreads();
#pragma unroll
    for (int par = 0; par < 2; ++par) {
      const int uoff = (((par * 4 + quad) ^ ub) << 4);
      half8 af[4], bf[4];
#pragma unroll
      for (int mf = 0; mf < 4; ++mf)
        af[mf] = *(const half8*)((const char*)As + (wm * 64 + mf * 16 + col) * 128 + uoff);
#pragma unroll
      for (int nf = 0; nf < 4; ++nf)
        bf[nf] = *(const half8*)((const char*)Bs + (wn * 64 + nf * 16 + col) * 128 + uoff);
#pragma unroll
      for (int mf = 0; mf < 4; ++mf)
#pragma unroll
        for (int nf = 0; nf < 4; ++nf)
          acc[mf][nf] = __builtin_amdgcn_mfma_f32_16x16x32_f16(af[mf], bf[nf], acc[mf][nf], 0, 0, 0);
    }
    __syncthreads();
  }

  float e2r[16];
#pragma unroll
  for (int mf = 0; mf < 4; ++mf)
#pragma unroll
    for (int v = 0; v < 4; ++v)
      e2r[mf * 4 + v] = e2[c0 + wm * 64 + mf * 16 + quad * 4 + v];

  float4* mbuf = (float4*)As;  // 4 KB reuse (post-barrier)
#pragma unroll
  for (int nf = 0; nf < 4; ++nf) {
    float d1 = 1e30f, d2 = 1e30f; int k1 = 0, k2 = 0;
#pragma unroll
    for (int mf = 0; mf < 4; ++mf)
#pragma unroll
      for (int v = 0; v < 4; ++v) {
        float d = fmaf(-2.0f, acc[mf][nf][v], e2r[mf * 4 + v]);
        int kc = c0 + wm * 64 + mf * 16 + quad * 4 + v;
        bool lt1 = d < d1, lt2 = d < d2;
        d2 = lt1 ? d1 : (lt2 ? d : d2);
        k2 = lt1 ? k1 : (lt2 ? kc : k2);
        d1 = lt1 ? d : d1;
        k1 = lt1 ? kc : k1;
      }
#pragma unroll
    for (int m = 16; m < 64; m <<= 1) {
      float od1 = __shfl_xor(d1, m, 64); int ok1 = __shfl_xor(k1, m, 64);
      float od2 = __shfl_xor(d2, m, 64); int ok2 = __shfl_xor(k2, m, 64);
      merge2(d1, k1, d2, k2, od1, ok1, od2, ok2);
    }
    if (quad == 0)
      mbuf[(wm * 2 + wn) * 64 + nf * 16 + col] =
          make_float4(d1, d2, __int_as_float(k1), __int_as_float(k2));
  }
  __syncthreads();
  if (tid < 128) {
    const int wnn = tid >> 6, zc = tid & 63;
    float4 a = mbuf[(0 * 2 + wnn) * 64 + zc];
    float4 b = mbuf[(1 * 2 + wnn) * 64 + zc];
    float d1 = a.x, d2 = a.y; int k1 = __float_as_int(a.z), k2 = __float_as_int(a.w);
    merge2(d1, k1, d2, k2, b.x, __float_as_int(b.z), b.y, __float_as_int(b.w));
    // [zt][ct][row_local]: tid 0..127 -> one contiguous 2 KB store run
    top2[((size_t)zt * 64 + ct) * 128 + tid] =
        make_float4(d1, d2, __int_as_float(k1), __int_as_float(k2));
  }
}

// ---------- fused refine + gather + STE + per-row loss; 64 sublists/row ----------
__global__ __launch_bounds__(256) void k_refine_gather(
    const float* __restrict__ z, const float* __restrict__ emb_n,
    const float* __restrict__ e2, const float4* __restrict__ top2,
    float* __restrict__ out0, float* __restrict__ idx_out,
    float* __restrict__ lsum, int* __restrict__ wl_row,
    unsigned long long* __restrict__ wl_mask, double* __restrict__ wl_best,
    int* __restrict__ wl_bk, int* __restrict__ n_flag) {
  __shared__ float zr[4][D];
  __shared__ float4 t2s[4][64];
  const int t = threadIdx.x;
  const int w = t >> 6, l = t & 63;
  const int row = blockIdx.x * 4 + w;
  float4 zv = ((const float4*)(z + (size_t)row * D))[l];
  float s = wave_sum(dot4(zv, zv));
  float inv = 1.0f / sqrtf(s + 1e-12f);
  float4 zn = make_float4(zv.x * inv, zv.y * inv, zv.z * inv, zv.w * inv);
  ((float4*)zr[w])[l] = zn;
  // coalesced top2 stage: thread t loads (ct = t>>2, local row = t&3)
  {
    const int zt = (blockIdx.x * 4) >> 7;
    const int rb = (blockIdx.x * 4) & 127;
    t2s[t & 3][t >> 2] = top2[((size_t)zt * 64 + (t >> 2)) * 128 + rb + (t & 3)];
  }
  __syncthreads();

  float4 e = t2s[w][l];
  const float ad1 = e.x, ad2 = e.y;
  const int ck1 = __float_as_int(e.z), ck2 = __float_as_int(e.w);
  const float d1g = wave_min_f(ad1);
  const float win = d1g + 2.0f * MARGIN;

  double best = 1e300; int bk = 0x7fffffff;
  unsigned long long m1 = __ballot(ad1 <= win);
  unsigned long long m2 = __ballot(ad2 <= win);  // sublist rescan mask (64 bits)
#pragma unroll 1
  for (int slot = 0; slot < 2; ++slot) {
    unsigned long long mm = slot ? m2 : m1;
    while (mm) {
      int ln = __builtin_ctzll(mm); mm &= mm - 1;
      int k = __shfl(slot ? ck2 : ck1, ln, 64);
      float4 e4 = ((const float4*)(emb_n + (size_t)k * D))[l];
      float4 z4 = ((const float4*)zr[w])[l];
      double p = (double)e4.x * (double)z4.x + (double)e4.y * (double)z4.y +
                 (double)e4.z * (double)z4.z + (double)e4.w * (double)z4.w;
#pragma unroll
      for (int off = 32; off; off >>= 1) p += __shfl_xor(p, off, 64);
      double dd = (double)e2[k] - 2.0 * p;
      if (dd < best || (dd == best && k < bk)) { best = dd; bk = k; }
    }
  }
  float4 q = ((const float4*)(emb_n + (size_t)bk * D))[l];
  float4 o;
  o.x = zv.x + (q.x - zv.x); o.y = zv.y + (q.y - zv.y);
  o.z = zv.z + (q.z - zv.z); o.w = zv.w + (q.w - zv.w);
  ((float4*)(out0 + (size_t)row * D))[l] = o;
  float dx = q.x - zn.x, dy = q.y - zn.y, dz = q.z - zn.z, dw = q.w - zn.w;
  float lp = wave_sum(dx * dx + dy * dy + dz * dz + dw * dw);
  if (l == 0) {
    lsum[row] = lp;
    idx_out[row] = (float)bk;
    if (m2) {  // some sublist's 3rd+ code could still be in the window
      int p = atomicAdd(n_flag, 1);
      wl_row[p] = row; wl_mask[p] = m2; wl_best[p] = best; wl_bk[p] = bk;
    }
  }
}

// ---------- exact fp64 rescan of flagged sublists (128 codes, 2 thr/code) ----------
__global__ __launch_bounds__(256) void k_rescan(
    const float* __restrict__ z, const float* __restrict__ emb_n,
    const float* __restrict__ e2, const int* __restrict__ wl_row,
    const unsigned long long* __restrict__ wl_mask,
    const double* __restrict__ wl_best, const int* __restrict__ wl_bk,
    const int* __restrict__ n_flag, float* __restrict__ idx_out,
    float* __restrict__ out0, float* __restrict__ lsum) {
  __shared__ float zr[D];
  __shared__ double ph[128];
  __shared__ double sd[4];
  __shared__ int si[4];
  __shared__ int s_bk;
  const int tid = threadIdx.x;
  const int nf = *n_flag;
  for (int wi = blockIdx.x; wi < nf; wi += gridDim.x) {
    const int row = wl_row[wi];
    unsigned long long mask = wl_mask[wi];   // block-uniform
    __syncthreads();  // protect zr/ph across iterations
    if (tid < 64) {
      float4 zv = ((const float4*)(z + (size_t)row * D))[tid];
      float s = wave_sum(dot4(zv, zv));
      float inv = 1.0f / sqrtf(s + 1e-12f);
      ((float4*)zr)[tid] = make_float4(zv.x * inv, zv.y * inv, zv.z * inv, zv.w * inv);
    }
    __syncthreads();
    double best = wl_best[wi]; int bk = wl_bk[wi];
    while (mask) {
      const int sl = __builtin_ctzll(mask); mask &= mask - 1;
      const int code = (sl << 7) + (tid & 127);
      const int half = tid >> 7;
      const float4* ev = (const float4*)(emb_n + (size_t)code * D) + half * 32;
      const float4* zf = ((const float4*)zr) + half * 32;
      double a0 = 0.0, a1 = 0.0;
#pragma unroll 8
      for (int i = 0; i < 32; i += 2) {
        float4 e0 = ev[i], e1 = ev[i + 1], z0 = zf[i], z1 = zf[i + 1];
        a0 += (double)e0.x * (double)z0.x + (double)e0.y * (double)z0.y +
              (double)e0.z * (double)z0.z + (double)e0.w * (double)z0.w;
        a1 += (double)e1.x * (double)z1.x + (double)e1.y * (double)z1.y +
              (double)e1.z * (double)z1.z + (double)e1.w * (double)z1.w;
      }
      double p = a0 + a1;
      if (half) ph[tid & 127] = p;
      __syncthreads();
      if (!half) {
        double dd = (double)e2[code] - 2.0 * (p + ph[tid]);
        if (dd < best || (dd == best && code < bk)) { best = dd; bk = code; }
      }
      __syncthreads();
    }
#pragma unroll
    for (int off = 32; off; off >>= 1) {
      double od = __shfl_xor(best, off, 64); int ok = __shfl_xor(bk, off, 64);
      if (od < best || (od == best && ok < bk)) { best = od; bk = ok; }
    }
    if ((tid & 63) == 0) { sd[tid >> 6] = best; si[tid >> 6] = bk; }
    __syncthreads();
    if (tid == 0) {
#pragma unroll
      for (int q = 1; q < 4; ++q)
        if (sd[q] < best || (sd[q] == best && si[q] < bk)) { best = sd[q]; bk = si[q]; }
      s_bk = bk;
      idx_out[row] = (float)bk;
    }
    __syncthreads();
    const int fk = s_bk;
    if (tid < 64) {
      float4 zv = ((const float4*)(z + (size_t)row * D))[tid];
      float4 zn = ((const float4*)zr)[tid];
      float4 q = ((const float4*)(emb_n + (size_t)fk * D))[tid];
      float4 o;
      o.x = zv.x + (q.x - zv.x); o.y = zv.y + (q.y - zv.y);
      o.z = zv.z + (q.z - zv.z); o.w = zv.w + (q.w - zv.w);
      ((float4*)(out0 + (size_t)row * D))[tid] = o;
      float dx = q.x - zn.x, dy = q.y - zn.y, dz = q.z - zn.z, dw = q.w - zn.w;
      float lp = wave_sum(dx * dx + dy * dy + dz * dz + dw * dw);
      if (tid == 0) lsum[row] = lp;
    }
  }
}

// ---------- final reduce: loss = 1.25 * sum(lsum) / (N*D) ----------
__global__ __launch_bounds__(256) void k_reduce(const float* __restrict__ lsum,
                                                float* __restrict__ loss_out,
                                                float inv_cnt) {
  __shared__ float ws4[4];
  float s = 0.0f;
  const float4* p = (const float4*)lsum;
  for (int i = threadIdx.x; i < NROW / 4; i += 256) {
    float4 v = p[i];
    s += (v.x + v.y) + (v.z + v.w);
  }
  s = wave_sum(s);
  if ((threadIdx.x & 63) == 0) ws4[threadIdx.x >> 6] = s;
  __syncthreads();
  if (threadIdx.x == 0) {
    float m = ((ws4[0] + ws4[1]) + (ws4[2] + ws4[3])) * inv_cnt;
    *loss_out = 0.25f * m + m;
  }
}

// ---------- fallback fp32 path (round-1, proven) ----------
__device__ __forceinline__ int sw_f(int row, int d4) { return row * D + 4 * (d4 ^ (row & 7)); }
__global__ __launch_bounds__(256, 1) void k_argmin_f32(const float* __restrict__ z,
                                                       const float* __restrict__ emb_n,
                                                       const float* __restrict__ e2,
                                                       float* __restrict__ idx_out, int K) {
  extern __shared__ float smem[];
  float* zs = smem; float* es = smem + 64 * D;
  int tid = threadIdx.x; int w = tid >> 6, l = tid & 63;
  size_t r0 = (size_t)blockIdx.x * 64;
#pragma unroll
  for (int i = 0; i < 16; ++i) {
    int row = 4 * i + w;
    float4 v = ((const float4*)(z + (r0 + row) * D))[l];
    float s = wave_sum(dot4(v, v));
    float inv = 1.0f / sqrtf(s + 1e-12f);
    v.x *= inv; v.y *= inv; v.z *= inv; v.w *= inv;
    *(float4*)(&zs[sw_f(row, l)]) = v;
  }
  __syncthreads();
  int tc = tid & 15, tr = tid >> 4;
  float bestd[4] = {1e30f, 1e30f, 1e30f, 1e30f};
  int bestk[4] = {0, 0, 0, 0};
  for (int k0 = 0; k0 < K; k0 += 64) {
#pragma unroll
    for (int i = 0; i < 16; ++i) {
      int row = 4 * i + w;
      float4 v = ((const float4*)(emb_n + (size_t)(k0 + row) * D))[l];
      *(float4*)(&es[sw_f(row, l)]) = v;
    }
    __syncthreads();
    float acc[4][4] = {};
#pragma unroll 4
    for (int d4 = 0; d4 < 64; ++d4) {
      float4 zv[4], ev[4];
#pragma unroll
      for (int i = 0; i < 4; ++i) zv[i] = *(const float4*)(&zs[sw_f(tr + 16 * i, d4)]);
#pragma unroll
      for (int jx = 0; jx < 4; ++jx) ev[jx] = *(const float4*)(&es[sw_f(tc + 16 * jx, d4)]);
#pragma unroll
      for (int i = 0; i < 4; ++i)
#pragma unroll
        for (int jx = 0; jx < 4; ++jx)
          acc[i][jx] = fmaf(zv[i].x, ev[jx].x, fmaf(zv[i].y, ev[jx].y,
                       fmaf(zv[i].z, ev[jx].z, fmaf(zv[i].w, ev[jx].w, acc[i][jx]))));
    }
#pragma unroll
    for (int jx = 0; jx < 4; ++jx) {
      int k = k0 + tc + 16 * jx;
      float ek = e2[k];
#pragma unroll
      for (int i = 0; i < 4; ++i) {
        float dd = fmaf(-2.0f, acc[i][jx], ek);
        if (dd < bestd[i]) { bestd[i] = dd; bestk[i] = k; }
      }
    }
    __syncthreads();
  }
#pragma unroll
  for (int i = 0; i < 4; ++i) {
    float dd = bestd[i]; int kkk = bestk[i];
#pragma unroll
    for (int off = 1; off < 16; off <<= 1) {
      float od = __shfl_xor(dd, off, 64); int ok = __shfl_xor(kkk, off, 64);
      if (od < dd || (od == dd && ok < kkk)) { dd = od; kkk = ok; }
    }
    if (tc == 0) idx_out[r0 + tr + 16 * i] = (float)kkk;
  }
}

__global__ __launch_bounds__(256) void k_gather(const float* __restrict__ z,
                                                const float* __restrict__ emb_n,
                                                const float* __restrict__ idx_f,
                                                float* __restrict__ out0,
                                                float* __restrict__ loss_acc) {
  __shared__ float wsum[4];
  int w = threadIdx.x >> 6, l = threadIdx.x & 63;
  int row = blockIdx.x * 4 + w;
  float4 zv = ((const float4*)(z + (size_t)row * D))[l];
  float s = wave_sum(dot4(zv, zv));
  float inv = 1.0f / sqrtf(s + 1e-12f);
  int k = (int)idx_f[row];
  float4 q = ((const float4*)(emb_n + (size_t)k * D))[l];
  float4 o;
  o.x = zv.x + (q.x - zv.x); o.y = zv.y + (q.y - zv.y);
  o.z = zv.z + (q.z - zv.z); o.w = zv.w + (q.w - zv.w);
  ((float4*)(out0 + (size_t)row * D))[l] = o;
  float dx = q.x - zv.x * inv, dy = q.y - zv.y * inv;
  float dz = q.z - zv.z * inv, dw = q.w - zv.w * inv;
  float lp = wave_sum(dx * dx + dy * dy + dz * dz + dw * dw);
  if (l == 0) wsum[w] = lp;
  __syncthreads();
  if (threadIdx.x == 0) atomicAdd(loss_acc, wsum[0] + wsum[1] + wsum[2] + wsum[3]);
}

__global__ void k_final(const float* __restrict__ loss_acc,
                        float* __restrict__ loss_out, float inv_cnt) {
  float m = *loss_acc * inv_cnt;
  *loss_out = 0.25f * m + m;
}

extern "C" void kernel_launch(void* const* d_in, const int* in_sizes, int n_in,
                              void* d_out, int out_size, void* d_ws, size_t ws_size,
                              hipStream_t stream) {
  const float* z = (const float*)d_in[0];
  const float* emb = (const float*)d_in[1];
  int N = in_sizes[0] / D;  // 16384
  int K = in_sizes[1] / D;  // 8192

  float* out0 = (float*)d_out;
  float* loss_out = out0 + (size_t)N * D;
  float* idx_out = loss_out + 1;

  char* ws = (char*)d_ws;
  float* emb_n = (float*)ws;                            // 8 MB
  float* e2 = (float*)(ws + 8388608);                   // 32 KB
  float* loss_acc = (float*)(ws + 8421376);             // 4 B (fallback)
  int* n_flag = (int*)(ws + 8421380);                   // 4 B
  float* lsum = (float*)(ws + 8421392);                 // 64 KB
  _Float16* Bb = (_Float16*)(ws + 8486928);             // codes fp16, 4 MB
  _Float16* Ab = (_Float16*)(ws + 12681232);            // z fp16, 8 MB
  float4* top2 = (float4*)(ws + 21069840);              // [zt][ct][128], 16 MB
  const size_t NEED = 37847056;
  // Ab dead after gemm -> worklist arrays (row/mask/best/bk)
  int* wl_row = (int*)Ab;
  unsigned long long* wl_mask = (unsigned long long*)((char*)Ab + 65536);
  double* wl_best = (double*)((char*)Ab + 196608);
  int* wl_bk = (int*)((char*)Ab + 327680);

  const float inv_cnt = 1.0f / (float)((size_t)N * D);
  hipMemsetAsync(loss_acc, 0, 8, stream);  // zero loss_acc + n_flag
  if (ws_size >= NEED) {
    k_prep<<<K / 4 + N / 4, 256, 0, stream>>>(emb, z, emb_n, e2, Bb, Ab);
    k_gemm_argmin6<<<(K / 128) * (N / 128), 256, 0, stream>>>(Bb, Ab, e2, top2);
    k_refine_gather<<<N / 4, 256, 0, stream>>>(z, emb_n, e2, top2, out0, idx_out,
                                               lsum, wl_row, wl_mask, wl_best,
                                               wl_bk, n_flag);
    k_rescan<<<1024, 256, 0, stream>>>(z, emb_n, e2, wl_row, wl_mask, wl_best,
                                       wl_bk, n_flag, idx_out, out0, lsum);
    k_reduce<<<1, 256, 0, stream>>>(lsum, loss_out, inv_cnt);
  } else {
    k_prep<<<K / 4 + N / 4, 256, 0, stream>>>(emb, z, emb_n, e2, Bb, Ab);
    k_argmin_f32<<<N / 64, 256, 131072, stream>>>(z, emb_n, e2, idx_out, K);
    k_gather<<<N / 4, 256, 0, stream>>>(z, emb_n, idx_out, out0, loss_acc);
    k_final<<<1, 1, 0, stream>>>(loss_acc, loss_out, inv_cnt);
  }
}